// Round 7
// baseline (4352.635 us; speedup 1.0000x reference)
//
#include <hip/hip_runtime.h>
#include <math.h>

#define VOCAB 32000
#define EMB   256
#define HID   512
#define NB    32
#define TT    128
#define TM1   127
#define SS    128
#define NROWS (TM1*NB)     // 4064
#define NT128 250          // 32000/128
#define NLSTM 64           // lstm blocks (8 units each)
#define NATTN 32
#define NFC   160
#define NBLK  256

// ---- workspace layout (float32 offsets) ----
#define OFF_ENCW 0          // bf16 [32][128][512] enc@attnW_enc^T + attnb
#define OFF_AWQT 1048576    // f32  [512][512]  attnW[:, :512] transposed
#define OFF_H0B  1310720    // bf16 ring [8][32][512] h0
#define OFF_H1B  1376256    // bf16 ring [2][32][512] h1
#define OFF_C0   1392640    // f32  [512][32]
#define OFF_C1   1409024    // f32  [512][32]
#define OFF_G0X  1425408    // bf16 [127][2048][32]  emb@Wih0^T + biases
#define OFF_CATB 5586944    // bf16 [4096][1024]  (h1 history ∥ weighted)
#define OFF_PART 7684096    // float2 [4096][250]
#define OFF_NLL  9732096
#define OFF_CNT  9736160
#define OFF_FLAGS 9740224   // ints: arr1[64*32] arr2[64*32] arr3[32*32] = 5120

#define SMEM_BYTES 119808

typedef __attribute__((ext_vector_type(8))) short short8;
typedef __attribute__((ext_vector_type(4))) float f32x4;
typedef unsigned long long ull_t;

__device__ __forceinline__ float sigm(float x){ return 1.f/(1.f + __expf(-x)); }
__device__ __forceinline__ float tanh_f(float x){
    x = fminf(fmaxf(x, -15.f), 15.f);
    float e = __expf(2.f*x);
    return (e-1.f)/(e+1.f);
}
__device__ __forceinline__ unsigned short f2b(float f){
    union{float f; unsigned u;} x{f};
    unsigned r = (x.u + 0x7fff + ((x.u>>16)&1)) >> 16;
    return (unsigned short)r;
}
__device__ __forceinline__ float b2f(unsigned short b){
    union{unsigned u; float f;} x{(unsigned)b<<16};
    return x.f;
}
__device__ __forceinline__ uint4 pack8(const float4 f0, const float4 f1){
    uint4 r;
    r.x = ((unsigned)f2b(f0.x)) | ((unsigned)f2b(f0.y)<<16);
    r.y = ((unsigned)f2b(f0.z)) | ((unsigned)f2b(f0.w)<<16);
    r.z = ((unsigned)f2b(f1.x)) | ((unsigned)f2b(f1.y)<<16);
    r.w = ((unsigned)f2b(f1.z)) | ((unsigned)f2b(f1.w)<<16);
    return r;
}
__device__ __forceinline__ ull_t cohl(const ull_t* p){
    return __hip_atomic_load((ull_t*)p, __ATOMIC_RELAXED, __HIP_MEMORY_SCOPE_AGENT);
}
__device__ __forceinline__ void cohs(ull_t* p, ull_t v){
    __hip_atomic_store(p, v, __ATOMIC_RELAXED, __HIP_MEMORY_SCOPE_AGENT);
}
__device__ __forceinline__ int cohli(const int* p){
    return __hip_atomic_load((int*)p, __ATOMIC_RELAXED, __HIP_MEMORY_SCOPE_AGENT);
}
__device__ __forceinline__ void cohsi(int* p, int v){
    __hip_atomic_store(p, v, __ATOMIC_RELAXED, __HIP_MEMORY_SCOPE_AGENT);
}
__device__ __forceinline__ short8 cohl16(const unsigned short* p){
    union { ull_t u[2]; short8 s; } a;
    a.u[0] = cohl((const ull_t*)p);
    a.u[1] = cohl((const ull_t*)p + 1);
    return a.s;
}

// ------------------------------------------------------------------ init
__global__ void k_init(const float* __restrict__ hid, const float* __restrict__ cel,
                       float* __restrict__ ws){
    int idx = blockIdx.x*256 + threadIdx.x;
    if (idx < 2*HID*NB){
        int l = idx >> 14, r = idx & 16383;      // r = k*32+b
        int k = r >> 5, b = r & 31;
        float hv = 0.5f*(hid[(2*l)*(NB*HID) + b*HID + k] + hid[(2*l+1)*(NB*HID) + b*HID + k]);
        float cv = 0.5f*(cel[(2*l)*(NB*HID) + b*HID + k] + cel[(2*l+1)*(NB*HID) + b*HID + k]);
        unsigned short* hb = (unsigned short*)(ws + (l==0 ? OFF_H0B : OFF_H1B));
        hb[b*512 + k] = f2b(hv);                 // ring slot 0
        ws[(l==0 ? OFF_C0 : OFF_C1) + k*32 + b] = cv;
    } else {
        int j = idx - 2*HID*NB;
        if (j < 32*1024){                         // zero catb pad rows 4064..4095
            unsigned short* catb = (unsigned short*)(ws + OFF_CATB);
            catb[(size_t)4064*1024 + j] = 0;
        } else {
            int f = j - 32*1024;
            if (f < 5120) ((int*)(ws + OFF_FLAGS))[f] = 0;
        }
    }
}

// ------------------------------------------------------------------ prep
__global__ void k_prep(const float* __restrict__ attnW, float* __restrict__ ws){
    int idx = blockIdx.x*256 + threadIdx.x;      // 262144
    int k = idx >> 9, h = idx & 511;
    ws[OFF_AWQT + k*512 + h] = attnW[h*1024 + k];
}

// ---------------------------------------------- encW = enc @ attnW[:,512:]^T + attnb  (bf16)
__global__ void k_encw(const float* __restrict__ enc, const float* __restrict__ attnW,
                       const float* __restrict__ attnb, float* __restrict__ ws){
    __shared__ float As[64][33];
    __shared__ float Bs[64][33];
    int tid = threadIdx.x;
    int nt = blockIdx.x, mt = blockIdx.y;
    int m0 = mt*64, n0 = nt*64;
    int ty = tid >> 4, tx = tid & 15;
    float acc[4][4] = {};
    for (int kk = 0; kk < 16; ++kk){
        int k0 = kk*32;
        #pragma unroll
        for (int i = 0; i < 8; ++i){
            int idx = tid + i*256;
            int r = idx >> 5, k = idx & 31;
            As[r][k] = enc[(m0+r)*HID + k0 + k];
            Bs[r][k] = attnW[(n0+r)*1024 + 512 + k0 + k];
        }
        __syncthreads();
        #pragma unroll
        for (int k = 0; k < 32; ++k){
            float av[4], bv[4];
            #pragma unroll
            for (int i=0;i<4;i++) av[i] = As[ty*4+i][k];
            #pragma unroll
            for (int j=0;j<4;j++) bv[j] = Bs[tx*4+j][k];
            #pragma unroll
            for (int i=0;i<4;i++)
                #pragma unroll
                for (int j=0;j<4;j++) acc[i][j] += av[i]*bv[j];
        }
        __syncthreads();
    }
    unsigned short* encwb = (unsigned short*)(ws + OFF_ENCW);
    #pragma unroll
    for (int i=0;i<4;i++)
      #pragma unroll
      for (int j=0;j<4;j++){
        int m = m0 + ty*4+i, n = n0 + tx*4+j;
        encwb[(size_t)m*512 + n] = f2b(acc[i][j] + attnb[n]);
      }
}

// ------------------------- g0x[t][row][b] = emb[X[b,t]] @ Wih0^T + bih0 + bhh0  (bf16)
__global__ void k_g0x(const int* __restrict__ X, const float* __restrict__ emb,
                      const float* __restrict__ Wih0, const float* __restrict__ bih0,
                      const float* __restrict__ bhh0, float* __restrict__ ws){
    __shared__ float As[64][33];
    __shared__ float Bs[64][33];
    int tid = threadIdx.x;
    int nt = blockIdx.x, mt = blockIdx.y;
    int m0 = mt*64, n0 = nt*64;
    int ty = tid >> 4, tx = tid & 15;
    float acc[4][4] = {};
    for (int kk = 0; kk < 8; ++kk){
        int k0 = kk*32;
        #pragma unroll
        for (int i = 0; i < 8; ++i){
            int idx = tid + i*256;
            int r = idx >> 5, k = idx & 31;
            int m = m0 + r;
            int tok = (m < NROWS) ? X[(m&31)*TT + (m>>5)] : 0;
            As[r][k] = emb[(size_t)tok*EMB + k0 + k];
            Bs[r][k] = Wih0[(n0+r)*EMB + k0 + k];
        }
        __syncthreads();
        #pragma unroll
        for (int k = 0; k < 32; ++k){
            float av[4], bv[4];
            #pragma unroll
            for (int i=0;i<4;i++) av[i] = As[ty*4+i][k];
            #pragma unroll
            for (int j=0;j<4;j++) bv[j] = Bs[tx*4+j][k];
            #pragma unroll
            for (int i=0;i<4;i++)
                #pragma unroll
                for (int j=0;j<4;j++) acc[i][j] += av[i]*bv[j];
        }
        __syncthreads();
    }
    unsigned short* g0xb = (unsigned short*)(ws + OFF_G0X);
    #pragma unroll
    for (int i=0;i<4;i++){
        int m = m0 + ty*4+i;
        if (m >= NROWS) continue;
        int t = m >> 5, b = m & 31;
        #pragma unroll
        for (int j=0;j<4;j++){
            int n = n0 + tx*4+j;
            g0xb[((size_t)t*2048 + n)*32 + b] = f2b(acc[i][j] + bih0[n] + bhh0[n]);
        }
    }
}

// ------------------------------------------------------------------ mega kernel
// 64 lstm blocks (8 units, 96KB weights in LDS) + 32 attn + 160 fc workers.
// All shared mutable data through L3 via relaxed agent-scope atomics.
__global__ void __launch_bounds__(512, 1)
k_mega(const float* __restrict__ enc, const float* __restrict__ Whh0,
       const float* __restrict__ Wih1, const float* __restrict__ Whh1,
       const float* __restrict__ bih1, const float* __restrict__ bhh1,
       const float* __restrict__ v, const float* __restrict__ fcW,
       const float* __restrict__ fcb, float* ws)
{
    extern __shared__ __align__(16) char smem[];
    const int blk = blockIdx.x, tid = threadIdx.x;
    unsigned short* catb  = (unsigned short*)(ws + OFF_CATB);
    const unsigned short* g0xb  = (const unsigned short*)(ws + OFF_G0X);
    const unsigned short* encwb = (const unsigned short*)(ws + OFF_ENCW);
    unsigned short* h0b = (unsigned short*)(ws + OFF_H0B);   // [8][32][512]
    unsigned short* h1b = (unsigned short*)(ws + OFF_H1B);   // [2][32][512]
    int* arr1 = (int*)(ws + OFF_FLAGS);       // [64] stride 32
    int* arr2 = arr1 + 2048;                  // [64] stride 32
    int* arr3 = arr1 + 4096;                  // [32] stride 32

    if (blk < NLSTM){
        // ================= lstm: 8 units, 32 gate-rows =================
        unsigned short* Ws0 = (unsigned short*)smem;              // [32][512]  32 KB
        unsigned short* Ws1 = (unsigned short*)(smem + 32768);    // [32][1024] 64 KB
        float* red  = (float*)(smem + 98304);                     // [8][2][64][4] 16 KB
        float* gbuf = (float*)(smem + 114688);                    // [32][33]
        float* bs1  = (float*)(smem + 118912);                    // [32]
        unsigned short* hstage = (unsigned short*)(smem + 119040);// [32][8] 512 B
        const int u0 = blk*8;
        // ---- stage weights once ----
        {   // Ws0: 32 rows (g*8+j), K=512
            int n = tid >> 4, q = tid & 15;
            int g = n >> 3, j = n & 7;
            const float* src = Whh0 + ((size_t)(g*512 + u0 + j))*512 + q*32;
            #pragma unroll
            for (int c = 0; c < 4; ++c){
                float4 f0 = *(const float4*)(src + c*8);
                float4 f1 = *(const float4*)(src + c*8 + 4);
                int s = q*4 + c;
                *(uint4*)&Ws0[n*512 + ((s ^ (n&7))<<3)] = pack8(f0, f1);
            }
        }
        #pragma unroll
        for (int rr = 0; rr < 2; ++rr){   // Ws1: 32 rows, K=1024
            int n = (tid >> 5) + rr*16, q = tid & 31;
            int g = n >> 3, j = n & 7;
            int grow = g*512 + u0 + j;
            int k0 = q*32;
            const float* src = (k0 < 512) ? (Wih1 + (size_t)grow*512 + k0)
                                          : (Whh1 + (size_t)grow*512 + (k0-512));
            #pragma unroll
            for (int c = 0; c < 4; ++c){
                float4 f0 = *(const float4*)(src + c*8);
                float4 f1 = *(const float4*)(src + c*8 + 4);
                int s = q*4 + c;
                *(uint4*)&Ws1[n*1024 + ((s ^ (n&7))<<3)] = pack8(f0, f1);
            }
        }
        if (tid < 32){
            int g = tid >> 3, j = tid & 7;
            int gr = g*512 + u0 + j;
            bs1[tid] = bih1[gr] + bhh1[gr];
        }
        __syncthreads();

        const int w = tid >> 6, lane = tid & 63;
        const int kg = w & 3, mt2 = w >> 2;
        const int lr = lane & 15, lg = lane >> 4;
        const int gj = (tid >> 5) & 7, gb = tid & 31, gu = u0 + gj;

        for (int i = 0; i <= 127; ++i){
            // hoisted g0x loads for this step's gates (cover latency under MFMA)
            float gx0=0.f, gx1=0.f, gx2=0.f, gx3=0.f;
            if (i <= 126 && tid < 256){
                const unsigned short* gx = g0xb + (size_t)i*65536;
                gx0 = b2f(gx[(0*512+gu)*32 + gb]);
                gx1 = b2f(gx[(1*512+gu)*32 + gb]);
                gx2 = b2f(gx[(2*512+gu)*32 + gb]);
                gx3 = b2f(gx[(3*512+gu)*32 + gb]);
            }
            // ---------- part A: lstm0 step i ----------
            if (i <= 126){
                const unsigned short* hsrc = h0b + (i&7)*16384;
                f32x4 a0 = {0.f,0.f,0.f,0.f}, a1 = {0.f,0.f,0.f,0.f};
                #pragma unroll
                for (int ks = 0; ks < 4; ++ks){
                    int kk = kg*4 + ks;
                    short8 a = cohl16(hsrc + (mt2*16+lr)*512 + kk*32 + lg*8);
                    int sl = kk*4 + lg;
                    short8 b0 = *(const short8*)&Ws0[lr*512      + ((sl ^ (lr&7))<<3)];
                    short8 b1 = *(const short8*)&Ws0[(16+lr)*512 + ((sl ^ (lr&7))<<3)];
                    a0 = __builtin_amdgcn_mfma_f32_16x16x32_bf16(a, b0, a0, 0,0,0);
                    a1 = __builtin_amdgcn_mfma_f32_16x16x32_bf16(a, b1, a1, 0,0,0);
                }
                *(f32x4*)&red[((w*2+0)*64 + lane)*4] = a0;
                *(f32x4*)&red[((w*2+1)*64 + lane)*4] = a1;
                __syncthreads();
                #pragma unroll
                for (int rep = 0; rep < 2; ++rep){
                    int o = tid + rep*512;
                    int reg = o & 3, ln = (o>>2) & 63, nt2 = (o>>8) & 1, mtl = o >> 9;
                    float s = 0.f;
                    #pragma unroll
                    for (int kg2 = 0; kg2 < 4; ++kg2)
                        s += red[(((mtl*4+kg2)*2 + nt2)*64 + ln)*4 + reg];
                    int bb = mtl*16 + (ln>>4)*4 + reg;
                    int nn = nt2*16 + (ln & 15);
                    gbuf[bb*33 + nn] = s;
                }
                __syncthreads();
                if (tid < 256){
                    float gi = gbuf[gb*33 + 0*8 + gj] + gx0;
                    float gf = gbuf[gb*33 + 1*8 + gj] + gx1;
                    float gg = gbuf[gb*33 + 2*8 + gj] + gx2;
                    float go = gbuf[gb*33 + 3*8 + gj] + gx3;
                    float c  = ws[OFF_C0 + gu*32 + gb];
                    float cn = sigm(gf)*c + sigm(gi)*tanh_f(gg);
                    float hn = sigm(go)*tanh_f(cn);
                    ws[OFF_C0 + gu*32 + gb] = cn;
                    hstage[gb*8 + gj] = f2b(hn);
                }
                __syncthreads();
                if (tid < 64){
                    int b = tid >> 1, hf = tid & 1;
                    cohs((ull_t*)(h0b + ((i+1)&7)*16384 + b*512 + u0) + hf,
                         ((ull_t*)&hstage[b*8])[hf]);
                }
            }
            // ---------- all-poll-all barrier (publish h0[i+1]) ----------
            __syncthreads();            // drain h0 cohs stores (vmcnt 0)
            if (tid == 0) cohsi(arr1 + blk*32, i + 1);
            for (;;){
                int ok = 1;
                if (tid < NLSTM) ok = (cohli(arr1 + tid*32) >= i + 1);
                if (__syncthreads_and(ok)) break;
                __builtin_amdgcn_s_sleep(2);
            }
            // ---------- part B: lstm1 step i-1 ----------
            if (i >= 1){
                const unsigned short* h0src = h0b + (i&7)*16384;
                const unsigned short* h1src = h1b + ((i-1)&1)*16384;
                f32x4 a0 = {0.f,0.f,0.f,0.f}, a1 = {0.f,0.f,0.f,0.f};
                #pragma unroll
                for (int ks = 0; ks < 8; ++ks){
                    int kk = kg*8 + ks;
                    const unsigned short* hs = (kk < 16)
                        ? (h0src + (mt2*16+lr)*512 + kk*32 + lg*8)
                        : (h1src + (mt2*16+lr)*512 + (kk-16)*32 + lg*8);
                    short8 a = cohl16(hs);
                    int sl = kk*4 + lg;
                    short8 b0 = *(const short8*)&Ws1[lr*1024      + ((sl ^ (lr&7))<<3)];
                    short8 b1 = *(const short8*)&Ws1[(16+lr)*1024 + ((sl ^ (lr&7))<<3)];
                    a0 = __builtin_amdgcn_mfma_f32_16x16x32_bf16(a, b0, a0, 0,0,0);
                    a1 = __builtin_amdgcn_mfma_f32_16x16x32_bf16(a, b1, a1, 0,0,0);
                }
                *(f32x4*)&red[((w*2+0)*64 + lane)*4] = a0;
                *(f32x4*)&red[((w*2+1)*64 + lane)*4] = a1;
                __syncthreads();
                #pragma unroll
                for (int rep = 0; rep < 2; ++rep){
                    int o = tid + rep*512;
                    int reg = o & 3, ln = (o>>2) & 63, nt2 = (o>>8) & 1, mtl = o >> 9;
                    float s = 0.f;
                    #pragma unroll
                    for (int kg2 = 0; kg2 < 4; ++kg2)
                        s += red[(((mtl*4+kg2)*2 + nt2)*64 + ln)*4 + reg];
                    int bb = mtl*16 + (ln>>4)*4 + reg;
                    int nn = nt2*16 + (ln & 15);
                    gbuf[bb*33 + nn] = s;
                }
                __syncthreads();
                if (tid < 256){
                    float gi = gbuf[gb*33 + 0*8 + gj] + bs1[0*8 + gj];
                    float gf = gbuf[gb*33 + 1*8 + gj] + bs1[1*8 + gj];
                    float gg = gbuf[gb*33 + 2*8 + gj] + bs1[2*8 + gj];
                    float go = gbuf[gb*33 + 3*8 + gj] + bs1[3*8 + gj];
                    float c  = ws[OFF_C1 + gu*32 + gb];
                    float cn = sigm(gf)*c + sigm(gi)*tanh_f(gg);
                    float hn = sigm(go)*tanh_f(cn);
                    ws[OFF_C1 + gu*32 + gb] = cn;
                    hstage[gb*8 + gj] = f2b(hn);
                }
                __syncthreads();
                if (tid < 64){
                    int b = tid >> 1, hf = tid & 1;
                    ull_t val = ((ull_t*)&hstage[b*8])[hf];
                    cohs((ull_t*)(h1b + (i&1)*16384 + b*512 + u0) + hf, val);
                    cohs((ull_t*)(catb + ((size_t)((i-1)*32 + b) << 10) + u0) + hf, val);
                }
            }
            // ---------- publish h1/catb for attn ----------
            __syncthreads();            // drain
            if (tid == 0) cohsi(arr2 + blk*32, i + 1);
        }
    } else if (blk < NLSTM + NATTN){
        // ================= attention: one block per batch =================
        float* h1s  = (float*)smem;           // 512 f32
        float* hqv  = (float*)(smem + 2048);
        float* attv = (float*)(smem + 4096);  // 128
        float* rbuf = (float*)(smem + 4608);  // 2
        unsigned short* wst = (unsigned short*)(smem + 4736); // 512 bf16
        const int b = blk - NLSTM;
        const float* aWqT = ws + OFF_AWQT;
        for (int ta = 0; ta < TM1; ++ta){
            // wait: all lstm blocks at iter >= ta+2 (catb row ta complete)
            for (;;){
                int ok = 1;
                if (tid < NLSTM) ok = (cohli(arr2 + tid*32) >= ta + 2);
                if (__syncthreads_and(ok)) break;
                __builtin_amdgcn_s_sleep(2);
            }
            if (tid < 128){
                ull_t vq = cohl((const ull_t*)(catb + ((size_t)(ta*32 + b) << 10)) + tid);
                #pragma unroll
                for (int e = 0; e < 4; ++e)
                    h1s[tid*4 + e] = b2f((unsigned short)((vq >> (16*e)) & 0xffff));
            }
            __syncthreads();
            {
                float a0=0.f,a1=0.f,a2=0.f,a3=0.f;
                const float* ap = aWqT + tid;
                #pragma unroll 4
                for (int k = 0; k < 512; k += 4){
                    a0 += ap[(k+0)*512] * h1s[k+0];
                    a1 += ap[(k+1)*512] * h1s[k+1];
                    a2 += ap[(k+2)*512] * h1s[k+2];
                    a3 += ap[(k+3)*512] * h1s[k+3];
                }
                hqv[tid] = (a0+a1)+(a2+a3);
            }
            __syncthreads();
            {
                const int s = tid >> 2, q = tid & 3;
                const unsigned short* eb = encwb + ((size_t)(b*SS+s))*512 + q*128;
                const float* hq = hqv + q*128;
                const float* vp = v + q*128;
                float p0 = 0.f, p1 = 0.f;
                #pragma unroll 2
                for (int k = 0; k < 128; k += 2){
                    p0 += tanh_f(hq[k]   + b2f(eb[k]))   * vp[k];
                    p1 += tanh_f(hq[k+1] + b2f(eb[k+1])) * vp[k+1];
                }
                float p = p0 + p1;
                p += __shfl_xor(p, 1);
                p += __shfl_xor(p, 2);
                if (q == 0) attv[s] = p;
            }
            __syncthreads();
            float e0 = 0.f, e1 = 0.f;
            if (tid < 64){
                float m2 = fmaxf(attv[tid], attv[tid+64]);
                #pragma unroll
                for (int msk = 32; msk >= 1; msk >>= 1) m2 = fmaxf(m2, __shfl_xor(m2, msk));
                if (tid == 0) rbuf[0] = m2;
            }
            __syncthreads();
            float M = rbuf[0];
            if (tid < 64){
                e0 = __expf(attv[tid] - M);
                e1 = __expf(attv[tid+64] - M);
                float sum = e0 + e1;
                #pragma unroll
                for (int msk = 32; msk >= 1; msk >>= 1) sum += __shfl_xor(sum, msk);
                if (tid == 0) rbuf[1] = sum;
            }
            __syncthreads();
            if (tid < 64){
                float inv = 1.f / rbuf[1];
                attv[tid] = e0*inv; attv[tid+64] = e1*inv;
            }
            __syncthreads();
            {
                float w0=0.f,w1=0.f,w2=0.f,w3=0.f;
                const float* ebase = enc + ((size_t)b*SS)*512 + tid;
                #pragma unroll 4
                for (int s = 0; s < 128; s += 4){
                    w0 += attv[s]   * ebase[(s  )*512];
                    w1 += attv[s+1] * ebase[(s+1)*512];
                    w2 += attv[s+2] * ebase[(s+2)*512];
                    w3 += attv[s+3] * ebase[(s+3)*512];
                }
                wst[tid] = f2b((w0+w1)+(w2+w3));
            }
            __syncthreads();
            if (tid < 128)
                cohs((ull_t*)(catb + ((size_t)(ta*32 + b) << 10) + 512) + tid,
                     ((ull_t*)wst)[tid]);
            __syncthreads();            // drain weighted stores
            if (tid == 0) cohsi(arr3 + b*32, ta + 1);
        }
    } else {
        // ================= fc workers: 160 blocks, tiles mt-major =================
        unsigned short* As = (unsigned short*)smem;            // [128][32]
        unsigned short* Bs = (unsigned short*)(smem + 8192);
        float* eM = (float*)(smem + 16384);                    // [4][128]
        float* eS = (float*)(smem + 18432);
        const int lane = tid & 63, wid = tid >> 6;
        const int wr = wid >> 2, wc = wid & 3;
        const int lr = lane & 15, lg = lane >> 4;
        const int ar = tid >> 2, asi = tid & 3;   // A/B staging: row, 8-elem slot
        for (int f = blk - (NLSTM + NATTN); f < 32*NT128; f += NFC){
            const int mt = f / NT128, nt = f % NT128;
            const int m0 = mt*128, n0 = nt*128;
            const int need = min(4*mt + 4, TM1);
            for (;;){
                int ok = 1;
                if (tid < 32) ok = (cohli(arr3 + tid*32) >= need);
                if (__syncthreads_and(ok)) break;
                __builtin_amdgcn_s_sleep(64);
            }
            f32x4 acc[4][2];
            #pragma unroll
            for (int i2=0;i2<4;i2++){ acc[i2][0]=(f32x4){0.f,0.f,0.f,0.f}; acc[i2][1]=(f32x4){0.f,0.f,0.f,0.f}; }
            for (int kk = 0; kk < 32; ++kk){
                const int k0 = kk*32;
                short8 av_g = cohl16(catb + (size_t)(m0+ar)*1024 + k0 + asi*8);
                const float* bsrc = fcW + (size_t)(n0+ar)*1024 + k0 + asi*8;
                float4 bf0 = *(const float4*)(bsrc);
                float4 bf1 = *(const float4*)(bsrc+4);
                __syncthreads();
                *(short8*)&As[ar*32 + ((asi ^ ((ar>>1)&3))*8)] = av_g;
                *(uint4*)&Bs[ar*32 + ((asi ^ ((ar>>1)&3))*8)] = pack8(bf0, bf1);
                __syncthreads();
                short8 av[4], bv[2];
                #pragma unroll
                for (int mi=0; mi<4; ++mi){
                    int r = wr*64 + mi*16 + lr;
                    av[mi] = *(const short8*)&As[r*32 + ((lg ^ ((r>>1)&3))*8)];
                }
                #pragma unroll
                for (int ni=0; ni<2; ++ni){
                    int r = wc*32 + ni*16 + lr;
                    bv[ni] = *(const short8*)&Bs[r*32 + ((lg ^ ((r>>1)&3))*8)];
                }
                #pragma unroll
                for (int mi=0; mi<4; ++mi){
                    acc[mi][0] = __builtin_amdgcn_mfma_f32_16x16x32_bf16(av[mi], bv[0], acc[mi][0], 0,0,0);
                    acc[mi][1] = __builtin_amdgcn_mfma_f32_16x16x32_bf16(av[mi], bv[1], acc[mi][1], 0,0,0);
                }
            }
            float bias0 = fcb[n0 + wc*32 + 0*16 + lr];
            float bias1 = fcb[n0 + wc*32 + 1*16 + lr];
            __syncthreads();   // As/Bs done; eM/eS region independent but sync rows
            #pragma unroll
            for (int mi=0; mi<4; ++mi){
                #pragma unroll
                for (int reg=0; reg<4; ++reg){
                    float v0 = acc[mi][0][reg] + bias0;
                    float v1 = acc[mi][1][reg] + bias1;
                    float mx = fmaxf(v0, v1);
                    #pragma unroll
                    for (int msk=8; msk>=1; msk>>=1) mx = fmaxf(mx, __shfl_xor(mx, msk));
                    float sm = __expf(v0 - mx) + __expf(v1 - mx);
                    #pragma unroll
                    for (int msk=8; msk>=1; msk>>=1) sm += __shfl_xor(sm, msk);
                    if (lr == 0){
                        int rl = wr*64 + mi*16 + lg*4 + reg;
                        eM[wc*128 + rl] = mx;
                        eS[wc*128 + rl] = sm;
                    }
                }
            }
            __syncthreads();
            if (tid < 128){
                float M = eM[tid], S = eS[tid];
                #pragma unroll
                for (int q = 1; q < 4; ++q){
                    float m2 = eM[q*128 + tid], s2 = eS[q*128 + tid];
                    float mm = fmaxf(M, m2);
                    S = S*__expf(M - mm) + s2*__expf(m2 - mm);
                    M = mm;
                }
                float2* part = (float2*)(ws + OFF_PART);
                part[(size_t)(m0 + tid)*NT128 + nt] = make_float2(M, S);
            }
            __syncthreads();
        }
    }
}

// ------------------------------------------- per-row LSE combine + target logit
__global__ void k_row(const int* __restrict__ X, const float* __restrict__ fcW,
                      const float* __restrict__ fcb, float* __restrict__ ws){
    __shared__ float LM[256], LS[256];
    int m = blockIdx.x, tid = threadIdx.x;
    const float2* p = (const float2*)(ws + OFF_PART);
    float M = -3.4e38f, Ssum = 0.f;
    if (tid < NT128){
        float2 q = p[(size_t)m*NT128 + tid];
        M = q.x; Ssum = q.y;
    }
    LM[tid] = M; LS[tid] = Ssum;
    __syncthreads();
    for (int off = 128; off >= 1; off >>= 1){
        if (tid < off){
            float m1 = LM[tid], s1 = LS[tid];
            float m2 = LM[tid+off], s2 = LS[tid+off];
            float mm = fmaxf(m1, m2);
            LM[tid] = mm;
            LS[tid] = s1*__expf(m1-mm) + s2*__expf(m2-mm);
        }
        __syncthreads();
    }
    float lse = LM[0] + __logf(LS[0]);
    __syncthreads();
    int t = m >> 5, b = m & 31;
    int y = X[b*TT + t + 1];
    const unsigned short* cr = (const unsigned short*)(ws + OFF_CATB) + (size_t)m*1024;
    const float* wr = fcW + (size_t)y*1024;
    float a = 0.f;
    #pragma unroll
    for (int k = 0; k < 4; ++k) a += b2f(cr[tid*4+k]) * wr[tid*4+k];
    LM[tid] = a;
    __syncthreads();
    for (int off = 128; off >= 1; off >>= 1){
        if (tid < off) LM[tid] += LM[tid+off];
        __syncthreads();
    }
    if (tid == 0){
        float tl = LM[0] + fcb[y];
        float nll = lse - tl;
        int valid = (y != 0);
        ws[OFF_NLL + m] = valid ? nll : 0.f;
        ws[OFF_CNT + m] = valid ? 1.f : 0.f;
    }
}

// ------------------------------------------------------------------ finalize
__global__ void k_fin(const float* __restrict__ ws, float* __restrict__ out){
    __shared__ float red[256];
    int tid = threadIdx.x;
    float lt = 0.f;
    if (tid < TM1){
        float s = 0.f, c = 0.f;
        for (int b=0;b<NB;b++){
            s += ws[OFF_NLL + tid*NB + b];
            c += ws[OFF_CNT + tid*NB + b];
        }
        lt = s / fmaxf(c, 1.f);
    }
    red[tid] = lt;
    __syncthreads();
    for (int off=128; off>=1; off>>=1){
        if (tid < off) red[tid] += red[tid+off];
        __syncthreads();
    }
    if (tid == 0) out[0] = red[0] / (float)TM1;
}

// -------------------------------------------------------------------- launch
extern "C" void kernel_launch(void* const* d_in, const int* in_sizes, int n_in,
                              void* d_out, int out_size, void* d_ws, size_t ws_size,
                              hipStream_t stream) {
    const int*   X     = (const int*)  d_in[0];
    const float* enc   = (const float*)d_in[1];
    const float* hid   = (const float*)d_in[2];
    const float* cel   = (const float*)d_in[3];
    const float* emb   = (const float*)d_in[4];
    const float* Wih0  = (const float*)d_in[5];
    const float* Whh0  = (const float*)d_in[6];
    const float* bih0  = (const float*)d_in[7];
    const float* bhh0  = (const float*)d_in[8];
    const float* Wih1  = (const float*)d_in[9];
    const float* Whh1  = (const float*)d_in[10];
    const float* bih1  = (const float*)d_in[11];
    const float* bhh1  = (const float*)d_in[12];
    const float* attnW = (const float*)d_in[13];
    const float* attnb = (const float*)d_in[14];
    const float* v     = (const float*)d_in[15];
    const float* fcW   = (const float*)d_in[16];
    const float* fcb   = (const float*)d_in[17];
    float* ws  = (float*)d_ws;
    float* out = (float*)d_out;

    static int smem_set = 0;
    if (!smem_set){
        hipFuncSetAttribute((const void*)k_mega,
                            hipFuncAttributeMaxDynamicSharedMemorySize, SMEM_BYTES);
        smem_set = 1;
    }

    k_init<<<277, 256, 0, stream>>>(hid, cel, ws);
    k_prep<<<1024, 256, 0, stream>>>(attnW, ws);
    k_encw<<<dim3(8,64), 256, 0, stream>>>(enc, attnW, attnb, ws);
    k_g0x<<<dim3(32,64), 256, 0, stream>>>(X, emb, Wih0, bih0, bhh0, ws);

    void* args[] = {(void*)&enc, (void*)&Whh0, (void*)&Wih1, (void*)&Whh1,
                    (void*)&bih1, (void*)&bhh1, (void*)&v, (void*)&fcW,
                    (void*)&fcb, (void*)&ws};
    hipLaunchCooperativeKernel((const void*)k_mega, dim3(NBLK), dim3(512),
                               args, SMEM_BYTES, stream);

    k_row<<<NROWS, 256, 0, stream>>>(X, fcW, fcb, ws);
    k_fin<<<1, 256, 0, stream>>>(ws, out);
}

// Round 9
// 4158.680 us; speedup vs baseline: 1.0466x; 1.0466x over previous
//
#include <hip/hip_runtime.h>
#include <math.h>

#define VOCAB 32000
#define EMB   256
#define HID   512
#define NB    32
#define TT    128
#define TM1   127
#define SS    128
#define NROWS (TM1*NB)     // 4064
#define NT128 250          // 32000/128
#define NLSTM 64           // lstm blocks (8 units each)
#define NATTN 32

// ---- workspace layout (float32 offsets) ----
#define OFF_ENCW 0          // bf16 [32][128][512] enc@attnW_enc^T + attnb
#define OFF_AWQT 1048576    // f32  [512][512]  attnW[:, :512] transposed
#define OFF_H0B  1310720    // bf16 ring [8][32][512] h0
#define OFF_H1B  1376256    // bf16 ring [2][32][512] h1
#define OFF_C0   1392640    // f32  [512][32]
#define OFF_C1   1409024    // f32  [512][32]
#define OFF_G0X  1425408    // bf16 [127][2048][32]  emb@Wih0^T + biases
#define OFF_CATB 5586944    // bf16 [4096][1024]  (h1 history ∥ weighted)
#define OFF_PART 7684096    // float2 [4096][250]
#define OFF_NLL  9732096
#define OFF_CNT  9736160
#define OFF_FLAGS 9740224   // ints: arr1[64*32]

// LDS: Ws0 32K | Ws1 64K | red 32K | gbuf 8320 | bs1 128 | hst0 512 | hst1 512
#define SMEM_BYTES 140544

typedef __attribute__((ext_vector_type(8))) short short8;
typedef __attribute__((ext_vector_type(4))) float f32x4;
typedef unsigned long long ull_t;

__device__ __forceinline__ float sigm(float x){ return 1.f/(1.f + __expf(-x)); }
__device__ __forceinline__ float tanh_f(float x){
    x = fminf(fmaxf(x, -15.f), 15.f);
    float e = __expf(2.f*x);
    return (e-1.f)/(e+1.f);
}
__device__ __forceinline__ unsigned short f2b(float f){
    union{float f; unsigned u;} x{f};
    unsigned r = (x.u + 0x7fff + ((x.u>>16)&1)) >> 16;
    return (unsigned short)r;
}
__device__ __forceinline__ float b2f(unsigned short b){
    union{unsigned u; float f;} x{(unsigned)b<<16};
    return x.f;
}
__device__ __forceinline__ uint4 pack8(const float4 f0, const float4 f1){
    uint4 r;
    r.x = ((unsigned)f2b(f0.x)) | ((unsigned)f2b(f0.y)<<16);
    r.y = ((unsigned)f2b(f0.z)) | ((unsigned)f2b(f0.w)<<16);
    r.z = ((unsigned)f2b(f1.x)) | ((unsigned)f2b(f1.y)<<16);
    r.w = ((unsigned)f2b(f1.z)) | ((unsigned)f2b(f1.w)<<16);
    return r;
}
__device__ __forceinline__ ull_t cohl(const ull_t* p){
    return __hip_atomic_load((ull_t*)p, __ATOMIC_RELAXED, __HIP_MEMORY_SCOPE_AGENT);
}
__device__ __forceinline__ void cohs(ull_t* p, ull_t v){
    __hip_atomic_store(p, v, __ATOMIC_RELAXED, __HIP_MEMORY_SCOPE_AGENT);
}
__device__ __forceinline__ int cohli(const int* p){
    return __hip_atomic_load((int*)p, __ATOMIC_RELAXED, __HIP_MEMORY_SCOPE_AGENT);
}
__device__ __forceinline__ void cohsi(int* p, int v){
    __hip_atomic_store(p, v, __ATOMIC_RELAXED, __HIP_MEMORY_SCOPE_AGENT);
}
// coherent 16B store via two 8B relaxed atomic stores (sc0 sc1, L3-coherent)
__device__ __forceinline__ void cohs16(unsigned short* p, uint4 v){
    ull_t lo = ((ull_t)v.y << 32) | (ull_t)v.x;
    ull_t hi = ((ull_t)v.w << 32) | (ull_t)v.z;
    cohs((ull_t*)p, lo);
    cohs((ull_t*)p + 1, hi);
}

// ------------------------------------------------------------------ init
__global__ void k_init(const float* __restrict__ hid, const float* __restrict__ cel,
                       float* __restrict__ ws){
    int idx = blockIdx.x*256 + threadIdx.x;
    if (idx < 2*HID*NB){
        int l = idx >> 14, r = idx & 16383;      // r = k*32+b
        int k = r >> 5, b = r & 31;
        float hv = 0.5f*(hid[(2*l)*(NB*HID) + b*HID + k] + hid[(2*l+1)*(NB*HID) + b*HID + k]);
        float cv = 0.5f*(cel[(2*l)*(NB*HID) + b*HID + k] + cel[(2*l+1)*(NB*HID) + b*HID + k]);
        unsigned short* hb = (unsigned short*)(ws + (l==0 ? OFF_H0B : OFF_H1B));
        hb[b*512 + k] = f2b(hv);                 // ring slot 0
        ws[(l==0 ? OFF_C0 : OFF_C1) + k*32 + b] = cv;
    } else {
        int j = idx - 2*HID*NB;
        if (j < 32*1024){                         // zero catb pad rows 4064..4095
            unsigned short* catb = (unsigned short*)(ws + OFF_CATB);
            catb[(size_t)4064*1024 + j] = 0;
        } else {
            int f = j - 32*1024;
            if (f < 4096) ((int*)(ws + OFF_FLAGS))[f] = 0;
        }
    }
}

// ------------------------------------------------------------------ prep
__global__ void k_prep(const float* __restrict__ attnW, float* __restrict__ ws){
    int idx = blockIdx.x*256 + threadIdx.x;      // 262144
    int k = idx >> 9, h = idx & 511;
    ws[OFF_AWQT + k*512 + h] = attnW[h*1024 + k];
}

// ---------------------------------------------- encW = enc @ attnW[:,512:]^T + attnb  (bf16)
__global__ void k_encw(const float* __restrict__ enc, const float* __restrict__ attnW,
                       const float* __restrict__ attnb, float* __restrict__ ws){
    __shared__ float As[64][33];
    __shared__ float Bs[64][33];
    int tid = threadIdx.x;
    int nt = blockIdx.x, mt = blockIdx.y;
    int m0 = mt*64, n0 = nt*64;
    int ty = tid >> 4, tx = tid & 15;
    float acc[4][4] = {};
    for (int kk = 0; kk < 16; ++kk){
        int k0 = kk*32;
        #pragma unroll
        for (int i = 0; i < 8; ++i){
            int idx = tid + i*256;
            int r = idx >> 5, k = idx & 31;
            As[r][k] = enc[(m0+r)*HID + k0 + k];
            Bs[r][k] = attnW[(n0+r)*1024 + 512 + k0 + k];
        }
        __syncthreads();
        #pragma unroll
        for (int k = 0; k < 32; ++k){
            float av[4], bv[4];
            #pragma unroll
            for (int i=0;i<4;i++) av[i] = As[ty*4+i][k];
            #pragma unroll
            for (int j=0;j<4;j++) bv[j] = Bs[tx*4+j][k];
            #pragma unroll
            for (int i=0;i<4;i++)
                #pragma unroll
                for (int j=0;j<4;j++) acc[i][j] += av[i]*bv[j];
        }
        __syncthreads();
    }
    unsigned short* encwb = (unsigned short*)(ws + OFF_ENCW);
    #pragma unroll
    for (int i=0;i<4;i++)
      #pragma unroll
      for (int j=0;j<4;j++){
        int m = m0 + ty*4+i, n = n0 + tx*4+j;
        encwb[(size_t)m*512 + n] = f2b(acc[i][j] + attnb[n]);
      }
}

// ------------------------- g0x[t][row][b] = emb[X[b,t]] @ Wih0^T + bih0 + bhh0  (bf16)
__global__ void k_g0x(const int* __restrict__ X, const float* __restrict__ emb,
                      const float* __restrict__ Wih0, const float* __restrict__ bih0,
                      const float* __restrict__ bhh0, float* __restrict__ ws){
    __shared__ float As[64][33];
    __shared__ float Bs[64][33];
    int tid = threadIdx.x;
    int nt = blockIdx.x, mt = blockIdx.y;
    int m0 = mt*64, n0 = nt*64;
    int ty = tid >> 4, tx = tid & 15;
    float acc[4][4] = {};
    for (int kk = 0; kk < 8; ++kk){
        int k0 = kk*32;
        #pragma unroll
        for (int i = 0; i < 8; ++i){
            int idx = tid + i*256;
            int r = idx >> 5, k = idx & 31;
            int m = m0 + r;
            int tok = (m < NROWS) ? X[(m&31)*TT + (m>>5)] : 0;
            As[r][k] = emb[(size_t)tok*EMB + k0 + k];
            Bs[r][k] = Wih0[(n0+r)*EMB + k0 + k];
        }
        __syncthreads();
        #pragma unroll
        for (int k = 0; k < 32; ++k){
            float av[4], bv[4];
            #pragma unroll
            for (int i=0;i<4;i++) av[i] = As[ty*4+i][k];
            #pragma unroll
            for (int j=0;j<4;j++) bv[j] = Bs[tx*4+j][k];
            #pragma unroll
            for (int i=0;i<4;i++)
                #pragma unroll
                for (int j=0;j<4;j++) acc[i][j] += av[i]*bv[j];
        }
        __syncthreads();
    }
    unsigned short* g0xb = (unsigned short*)(ws + OFF_G0X);
    #pragma unroll
    for (int i=0;i<4;i++){
        int m = m0 + ty*4+i;
        if (m >= NROWS) continue;
        int t = m >> 5, b = m & 31;
        #pragma unroll
        for (int j=0;j<4;j++){
            int n = n0 + tx*4+j;
            g0xb[((size_t)t*2048 + n)*32 + b] = f2b(acc[i][j] + bih0[n] + bhh0[n]);
        }
    }
}

// ------------------------------------------------------------------ persistent scan
// 64 lstm blocks (8 units; lstm0(i) and lstm1(i-1) FUSED in one phase -> ONE
// barrier/step) + 32 attn blocks. h-state exchange via coherent loads/stores
// (sc0 sc1, L3 coherence point, no cache maintenance).
__global__ void __launch_bounds__(512, 1)
k_scan(const float* __restrict__ enc, const float* __restrict__ Whh0,
       const float* __restrict__ Wih1, const float* __restrict__ Whh1,
       const float* __restrict__ bih1, const float* __restrict__ bhh1,
       const float* __restrict__ v, float* ws)
{
    extern __shared__ __align__(16) char smem[];
    const int blk = blockIdx.x, tid = threadIdx.x;
    unsigned short* catb  = (unsigned short*)(ws + OFF_CATB);
    const unsigned short* g0xb  = (const unsigned short*)(ws + OFF_G0X);
    const unsigned short* encwb = (const unsigned short*)(ws + OFF_ENCW);
    unsigned short* h0b = (unsigned short*)(ws + OFF_H0B);   // [8][32][512]
    unsigned short* h1b = (unsigned short*)(ws + OFF_H1B);   // [2][32][512]
    int* arr1 = (int*)(ws + OFF_FLAGS);       // [64] stride 32 ints

    if (blk < NLSTM){
        unsigned short* Ws0 = (unsigned short*)smem;              // [32][512]  32 KB
        unsigned short* Ws1 = (unsigned short*)(smem + 32768);    // [32][1024] 64 KB
        float* red  = (float*)(smem + 98304);                     // [8w][4q][64][4] 32 KB
        float* gbuf = (float*)(smem + 131072);                    // [32][65]
        float* bs1  = (float*)(smem + 139392);                    // [32]
        unsigned short* hst0 = (unsigned short*)(smem + 139520);  // [32][8]
        unsigned short* hst1 = (unsigned short*)(smem + 140032);  // [32][8]
        const int u0 = blk*8;
        // ---- stage weights once ----
        {   // Ws0: 32 rows (g*8+j), K=512
            int n = tid >> 4, q = tid & 15;
            int g = n >> 3, j = n & 7;
            const float* src = Whh0 + ((size_t)(g*512 + u0 + j))*512 + q*32;
            #pragma unroll
            for (int c = 0; c < 4; ++c){
                float4 f0 = *(const float4*)(src + c*8);
                float4 f1 = *(const float4*)(src + c*8 + 4);
                int s = q*4 + c;
                *(uint4*)&Ws0[n*512 + ((s ^ (n&7))<<3)] = pack8(f0, f1);
            }
        }
        #pragma unroll
        for (int rr = 0; rr < 2; ++rr){   // Ws1: 32 rows, K=1024
            int n = (tid >> 5) + rr*16, q = tid & 31;
            int g = n >> 3, j = n & 7;
            int grow = g*512 + u0 + j;
            int k0 = q*32;
            const float* src = (k0 < 512) ? (Wih1 + (size_t)grow*512 + k0)
                                          : (Whh1 + (size_t)grow*512 + (k0-512));
            #pragma unroll
            for (int c = 0; c < 4; ++c){
                float4 f0 = *(const float4*)(src + c*8);
                float4 f1 = *(const float4*)(src + c*8 + 4);
                int s = q*4 + c;
                *(uint4*)&Ws1[n*1024 + ((s ^ (n&7))<<3)] = pack8(f0, f1);
            }
        }
        if (tid < 32){
            int g = tid >> 3, j = tid & 7;
            int gr = g*512 + u0 + j;
            bs1[tid] = bih1[gr] + bhh1[gr];
        }
        __syncthreads();

        const int w = tid >> 6, lane = tid & 63;
        const int kg = w & 3, mt2 = w >> 2;
        const int lr = lane & 15, lg = lane >> 4;
        const int half = tid >> 8, idx = tid & 255;
        const int gj = idx >> 5, gb = idx & 31, gu = u0 + gj;

        for (int i = 0; i <= 127; ++i){
            // prefetch g0x gate inputs (lstm0 half threads)
            float gx0=0.f, gx1=0.f, gx2=0.f, gx3=0.f;
            if (half == 0 && i <= 126){
                const unsigned short* gx = g0xb + (size_t)i*65536;
                gx0 = b2f(gx[(0*512+gu)*32 + gb]);
                gx1 = b2f(gx[(1*512+gu)*32 + gb]);
                gx2 = b2f(gx[(2*512+gu)*32 + gb]);
                gx3 = b2f(gx[(3*512+gu)*32 + gb]);
            }
            // ---- fused coherent gather: h0[i] (always) + h1[i-1] ----
            const unsigned short* p0 = h0b + (i&7)*16384 + (mt2*16+lr)*512 + kg*128 + lg*8;
            const unsigned short* p1 = h1b + ((i-1)&1)*16384 + (mt2*16+lr)*512 + kg*128 + lg*8;
            short8 A0[4], A1[4];
            #pragma unroll
            for (int ks = 0; ks < 4; ++ks){
                union { ull_t u[2]; short8 s; } a;
                a.u[0] = cohl((const ull_t*)(p0 + ks*32));
                a.u[1] = cohl((const ull_t*)(p0 + ks*32) + 1);
                A0[ks] = a.s;
            }
            #pragma unroll
            for (int ks = 0; ks < 4; ++ks){
                union { ull_t u[2]; short8 s; } a;
                a.u[0] = cohl((const ull_t*)(p1 + ks*32));
                a.u[1] = cohl((const ull_t*)(p1 + ks*32) + 1);
                A1[ks] = a.s;
            }

            f32x4 aL00 = {0.f,0.f,0.f,0.f}, aL01 = {0.f,0.f,0.f,0.f};
            f32x4 aL10 = {0.f,0.f,0.f,0.f}, aL11 = {0.f,0.f,0.f,0.f};
            if (i <= 126){          // lstm0 step i: h0[i] x Ws0
                #pragma unroll
                for (int ks = 0; ks < 4; ++ks){
                    int sl = (kg*4+ks)*4 + lg;
                    short8 b0 = *(const short8*)&Ws0[lr*512      + ((sl ^ (lr&7))<<3)];
                    short8 b1 = *(const short8*)&Ws0[(16+lr)*512 + ((sl ^ (lr&7))<<3)];
                    aL00 = __builtin_amdgcn_mfma_f32_16x16x32_bf16(A0[ks], b0, aL00, 0,0,0);
                    aL01 = __builtin_amdgcn_mfma_f32_16x16x32_bf16(A0[ks], b1, aL01, 0,0,0);
                }
            }
            if (i >= 1){            // lstm1 step i-1: h0[i] x Wih1-half + h1[i-1] x Whh1-half
                #pragma unroll
                for (int ks = 0; ks < 4; ++ks){
                    int sl = (kg*4+ks)*4 + lg;
                    short8 b0 = *(const short8*)&Ws1[lr*1024      + ((sl ^ (lr&7))<<3)];
                    short8 b1 = *(const short8*)&Ws1[(16+lr)*1024 + ((sl ^ (lr&7))<<3)];
                    aL10 = __builtin_amdgcn_mfma_f32_16x16x32_bf16(A0[ks], b0, aL10, 0,0,0);
                    aL11 = __builtin_amdgcn_mfma_f32_16x16x32_bf16(A0[ks], b1, aL11, 0,0,0);
                }
                #pragma unroll
                for (int ks = 0; ks < 4; ++ks){
                    int sl = ((16 + kg*4+ks)*4) + lg;
                    short8 b0 = *(const short8*)&Ws1[lr*1024      + ((sl ^ (lr&7))<<3)];
                    short8 b1 = *(const short8*)&Ws1[(16+lr)*1024 + ((sl ^ (lr&7))<<3)];
                    aL10 = __builtin_amdgcn_mfma_f32_16x16x32_bf16(A1[ks], b0, aL10, 0,0,0);
                    aL11 = __builtin_amdgcn_mfma_f32_16x16x32_bf16(A1[ks], b1, aL11, 0,0,0);
                }
            }
            *(f32x4*)&red[((w*4+0)*64 + lane)*4] = aL00;
            *(f32x4*)&red[((w*4+1)*64 + lane)*4] = aL01;
            *(f32x4*)&red[((w*4+2)*64 + lane)*4] = aL10;
            *(f32x4*)&red[((w*4+3)*64 + lane)*4] = aL11;
            __syncthreads();
            // reduce K-splits: 2048 outputs (2mt x 16b x 64 gate-cols)
            #pragma unroll
            for (int rep = 0; rep < 4; ++rep){
                int o = tid + rep*512;
                int reg = o & 3, ln = (o>>2) & 63, qq = (o>>8) & 3, mtl = (o>>10) & 1;
                float s = 0.f;
                #pragma unroll
                for (int kg2 = 0; kg2 < 4; ++kg2)
                    s += red[(((mtl*4+kg2)*4 + qq)*64 + ln)*4 + reg];
                int bb = mtl*16 + (ln>>4)*4 + reg;
                int nn = qq*16 + (ln & 15);
                gbuf[bb*65 + nn] = s;
            }
            __syncthreads();
            // gate phase: half 0 -> lstm0 (step i), half 1 -> lstm1 (step i-1)
            if (half == 0 ? (i <= 126) : (i >= 1)){
                float gi, gf, gg, go, c;
                if (half == 0){
                    gi = gbuf[gb*65 + 0*8 + gj] + gx0;
                    gf = gbuf[gb*65 + 1*8 + gj] + gx1;
                    gg = gbuf[gb*65 + 2*8 + gj] + gx2;
                    go = gbuf[gb*65 + 3*8 + gj] + gx3;
                    c  = ws[OFF_C0 + gu*32 + gb];
                } else {
                    gi = gbuf[gb*65 + 32 + 0*8 + gj] + bs1[0*8 + gj];
                    gf = gbuf[gb*65 + 32 + 1*8 + gj] + bs1[1*8 + gj];
                    gg = gbuf[gb*65 + 32 + 2*8 + gj] + bs1[2*8 + gj];
                    go = gbuf[gb*65 + 32 + 3*8 + gj] + bs1[3*8 + gj];
                    c  = ws[OFF_C1 + gu*32 + gb];
                }
                float cn = sigm(gf)*c + sigm(gi)*tanh_f(gg);
                float hn = sigm(go)*tanh_f(cn);
                if (half == 0){
                    ws[OFF_C0 + gu*32 + gb] = cn;
                    hst0[gb*8 + gj] = f2b(hn);
                } else {
                    ws[OFF_C1 + gu*32 + gb] = cn;
                    hst1[gb*8 + gj] = f2b(hn);
                }
            }
            __syncthreads();
            // publish: coherent stores
            if (tid < 32 && i <= 126){
                cohs16(h0b + ((i+1)&7)*16384 + tid*512 + u0, *(uint4*)&hst0[tid*8]);
            } else if (tid >= 32 && tid < 64 && i >= 1){
                int b = tid - 32;
                uint4 val = *(uint4*)&hst1[b*8];
                cohs16(h1b + (i&1)*16384 + b*512 + u0, val);
                cohs16(catb + ((size_t)((i-1)*32 + b) << 10) + u0, val);
            }
            __syncthreads();        // all waves' stores drained (vmcnt 0)
            if (tid == 0) cohsi(arr1 + blk*32, i + 1);
            // all-poll-all barrier
            for (;;){
                int ok = 1;
                if (tid < NLSTM) ok = (cohli(arr1 + tid*32) >= i + 1);
                if (__syncthreads_and(ok)) break;
                __builtin_amdgcn_s_sleep(2);
            }
        }
    } else {
        // ================= attention: one block per batch =================
        float* h1s  = (float*)smem;           // 512 f32
        float* hqv  = (float*)(smem + 2048);
        float* attv = (float*)(smem + 4096);  // 128
        float* rbuf = (float*)(smem + 4608);  // 2
        unsigned short* wst = (unsigned short*)(smem + 4736); // 512 bf16
        const int b = blk - NLSTM;
        const float* aWqT = ws + OFF_AWQT;
        for (int ta = 0; ta < TM1; ++ta){
            // wait: all lstm blocks finished iteration ta+1 (catb row ta h1-half done)
            for (;;){
                int ok = 1;
                if (tid < NLSTM) ok = (cohli(arr1 + tid*32) >= ta + 2);
                if (__syncthreads_and(ok)) break;
                __builtin_amdgcn_s_sleep(2);
            }
            if (tid < 128){
                ull_t vq = cohl((const ull_t*)(catb + ((size_t)(ta*32 + b) << 10)) + tid);
                #pragma unroll
                for (int e = 0; e < 4; ++e)
                    h1s[tid*4 + e] = b2f((unsigned short)((vq >> (16*e)) & 0xffff));
            }
            __syncthreads();
            {
                float a0=0.f,a1=0.f,a2=0.f,a3=0.f;
                const float* ap = aWqT + tid;
                #pragma unroll 4
                for (int k = 0; k < 512; k += 4){
                    a0 += ap[(k+0)*512] * h1s[k+0];
                    a1 += ap[(k+1)*512] * h1s[k+1];
                    a2 += ap[(k+2)*512] * h1s[k+2];
                    a3 += ap[(k+3)*512] * h1s[k+3];
                }
                hqv[tid] = (a0+a1)+(a2+a3);
            }
            __syncthreads();
            {
                const int s = tid >> 2, q = tid & 3;
                const unsigned short* eb = encwb + ((size_t)(b*SS+s))*512 + q*128;
                const float* hq = hqv + q*128;
                const float* vp = v + q*128;
                float p0 = 0.f, p1 = 0.f;
                #pragma unroll 2
                for (int k = 0; k < 128; k += 2){
                    p0 += tanh_f(hq[k]   + b2f(eb[k]))   * vp[k];
                    p1 += tanh_f(hq[k+1] + b2f(eb[k+1])) * vp[k+1];
                }
                float p = p0 + p1;
                p += __shfl_xor(p, 1);
                p += __shfl_xor(p, 2);
                if (q == 0) attv[s] = p;
            }
            __syncthreads();
            float e0 = 0.f, e1 = 0.f;
            if (tid < 64){
                float m2 = fmaxf(attv[tid], attv[tid+64]);
                #pragma unroll
                for (int msk = 32; msk >= 1; msk >>= 1) m2 = fmaxf(m2, __shfl_xor(m2, msk));
                if (tid == 0) rbuf[0] = m2;
            }
            __syncthreads();
            float M = rbuf[0];
            if (tid < 64){
                e0 = __expf(attv[tid] - M);
                e1 = __expf(attv[tid+64] - M);
                float sum = e0 + e1;
                #pragma unroll
                for (int msk = 32; msk >= 1; msk >>= 1) sum += __shfl_xor(sum, msk);
                if (tid == 0) rbuf[1] = sum;
            }
            __syncthreads();
            if (tid < 64){
                float inv = 1.f / rbuf[1];
                attv[tid] = e0*inv; attv[tid+64] = e1*inv;
            }
            __syncthreads();
            {
                float w0=0.f,w1=0.f,w2=0.f,w3=0.f;
                const float* ebase = enc + ((size_t)b*SS)*512 + tid;
                #pragma unroll 4
                for (int s = 0; s < 128; s += 4){
                    w0 += attv[s]   * ebase[(s  )*512];
                    w1 += attv[s+1] * ebase[(s+1)*512];
                    w2 += attv[s+2] * ebase[(s+2)*512];
                    w3 += attv[s+3] * ebase[(s+3)*512];
                }
                wst[tid] = f2b((w0+w1)+(w2+w3));
            }
            __syncthreads();
            if (tid < 128)
                cohs((ull_t*)(catb + ((size_t)(ta*32 + b) << 10) + 512) + tid,
                     ((ull_t*)wst)[tid]);
            __syncthreads();
        }
    }
}

// ------------------------------------------------------------------ fc MFMA GEMM + LSE partials
__global__ void __launch_bounds__(256)
k_fc(const float* __restrict__ fcW, const float* __restrict__ fcb, float* __restrict__ ws){
    __shared__ unsigned short As[128*32];
    __shared__ unsigned short Bs[128*32];
    __shared__ float eM[128], eS[128];
    const int tid = threadIdx.x;
    const int mt = blockIdx.x, nt = blockIdx.y;
    const int m0 = mt*128, n0 = nt*128;
    const unsigned short* catb = (const unsigned short*)(ws + OFF_CATB);
    const int lane = tid & 63, wid = tid >> 6;
    const int wr = wid >> 1, wc = wid & 1;
    const int lr = lane & 15, lg = lane >> 4;
    const int ar = tid & 127, ah = tid >> 7;
    const int br = tid >> 1,  bh = tid & 1;
    f32x4 acc[4][4];
    #pragma unroll
    for (int i=0;i<4;i++)
        #pragma unroll
        for (int j=0;j<4;j++) acc[i][j] = (f32x4){0.f,0.f,0.f,0.f};

    for (int kk = 0; kk < 32; ++kk){
        const int k0 = kk*32;
        uint4 a0 = *(const uint4*)(catb + (size_t)(m0+ar)*1024 + k0 + ah*16);
        uint4 a1 = *(const uint4*)(catb + (size_t)(m0+ar)*1024 + k0 + ah*16 + 8);
        const float* bsrc = fcW + (size_t)(n0+br)*1024 + k0 + bh*16;
        float4 f0 = *(const float4*)(bsrc);
        float4 f1 = *(const float4*)(bsrc+4);
        float4 f2 = *(const float4*)(bsrc+8);
        float4 f3 = *(const float4*)(bsrc+12);
        __syncthreads();
        {
            int swz = (ar>>1)&3;
            *(uint4*)&As[ar*32 + ((2*ah  )^swz)*8] = a0;
            *(uint4*)&As[ar*32 + ((2*ah+1)^swz)*8] = a1;
        }
        {
            uint4 p0, p1;
            p0.x = __builtin_amdgcn_perm(__float_as_uint(f0.y), __float_as_uint(f0.x), 0x07060302u);
            p0.y = __builtin_amdgcn_perm(__float_as_uint(f0.w), __float_as_uint(f0.z), 0x07060302u);
            p0.z = __builtin_amdgcn_perm(__float_as_uint(f1.y), __float_as_uint(f1.x), 0x07060302u);
            p0.w = __builtin_amdgcn_perm(__float_as_uint(f1.w), __float_as_uint(f1.z), 0x07060302u);
            p1.x = __builtin_amdgcn_perm(__float_as_uint(f2.y), __float_as_uint(f2.x), 0x07060302u);
            p1.y = __builtin_amdgcn_perm(__float_as_uint(f2.w), __float_as_uint(f2.z), 0x07060302u);
            p1.z = __builtin_amdgcn_perm(__float_as_uint(f3.y), __float_as_uint(f3.x), 0x07060302u);
            p1.w = __builtin_amdgcn_perm(__float_as_uint(f3.w), __float_as_uint(f3.z), 0x07060302u);
            int swz = (br>>1)&3;
            *(uint4*)&Bs[br*32 + ((2*bh  )^swz)*8] = p0;
            *(uint4*)&Bs[br*32 + ((2*bh+1)^swz)*8] = p1;
        }
        __syncthreads();
        short8 av[4], bv[4];
        #pragma unroll
        for (int mi=0; mi<4; ++mi){
            int r = wr*64 + mi*16 + lr;
            av[mi] = *(const short8*)&As[r*32 + ((lg ^ ((r>>1)&3))*8)];
        }
        #pragma unroll
        for (int ni=0; ni<4; ++ni){
            int r = wc*64 + ni*16 + lr;
            bv[ni] = *(const short8*)&Bs[r*32 + ((lg ^ ((r>>1)&3))*8)];
        }
        #pragma unroll
        for (int mi=0; mi<4; ++mi)
            #pragma unroll
            for (int ni=0; ni<4; ++ni)
                acc[mi][ni] = __builtin_amdgcn_mfma_f32_16x16x32_bf16(av[mi], bv[ni], acc[mi][ni], 0, 0, 0);
    }
    float bias[4];
    #pragma unroll
    for (int ni=0; ni<4; ++ni) bias[ni] = fcb[n0 + wc*64 + ni*16 + lr];
    float mxA[4][4], smA[4][4];
    #pragma unroll
    for (int mi=0; mi<4; ++mi){
        #pragma unroll
        for (int reg=0; reg<4; ++reg){
            float mx = -3.4e38f;
            #pragma unroll
            for (int ni=0; ni<4; ++ni) mx = fmaxf(mx, acc[mi][ni][reg] + bias[ni]);
            #pragma unroll
            for (int msk=8; msk>=1; msk>>=1) mx = fmaxf(mx, __shfl_xor(mx, msk));
            float sm = 0.f;
            #pragma unroll
            for (int ni=0; ni<4; ++ni) sm += __expf(acc[mi][ni][reg] + bias[ni] - mx);
            #pragma unroll
            for (int msk=8; msk>=1; msk>>=1) sm += __shfl_xor(sm, msk);
            mxA[mi][reg] = mx; smA[mi][reg] = sm;
            if (wc == 0 && lr == 0){
                int rl = wr*64 + mi*16 + lg*4 + reg;
                eM[rl] = mx; eS[rl] = sm;
            }
        }
    }
    __syncthreads();
    if (wc == 1 && lr == 0){
        float2* part = (float2*)(ws + OFF_PART);
        #pragma unroll
        for (int mi=0; mi<4; ++mi){
            #pragma unroll
            for (int reg=0; reg<4; ++reg){
                int rl = wr*64 + mi*16 + lg*4 + reg;
                float m0v = eM[rl], s0 = eS[rl];
                float m1v = mxA[mi][reg], s1 = smA[mi][reg];
                float M = fmaxf(m0v, m1v);
                float S = s0*__expf(m0v - M) + s1*__expf(m1v - M);
                part[(size_t)(m0 + rl)*NT128 + nt] = make_float2(M, S);
            }
        }
    }
}

// ------------------------------------------- per-row LSE combine + target logit
__global__ void k_row(const int* __restrict__ X, const float* __restrict__ fcW,
                      const float* __restrict__ fcb, float* __restrict__ ws){
    __shared__ float LM[256], LS[256];
    int m = blockIdx.x, tid = threadIdx.x;
    const float2* p = (const float2*)(ws + OFF_PART);
    float M = -3.4e38f, Ssum = 0.f;
    if (tid < NT128){
        float2 q = p[(size_t)m*NT128 + tid];
        M = q.x; Ssum = q.y;
    }
    LM[tid] = M; LS[tid] = Ssum;
    __syncthreads();
    for (int off = 128; off >= 1; off >>= 1){
        if (tid < off){
            float m1 = LM[tid], s1 = LS[tid];
            float m2 = LM[tid+off], s2 = LS[tid+off];
            float mm = fmaxf(m1, m2);
            LM[tid] = mm;
            LS[tid] = s1*__expf(m1-mm) + s2*__expf(m2-mm);
        }
        __syncthreads();
    }
    float lse = LM[0] + __logf(LS[0]);
    __syncthreads();
    int t = m >> 5, b = m & 31;
    int y = X[b*TT + t + 1];
    const unsigned short* cr = (const unsigned short*)(ws + OFF_CATB) + (size_t)m*1024;
    const float* wr = fcW + (size_t)y*1024;
    float a = 0.f;
    #pragma unroll
    for (int k = 0; k < 4; ++k) a += b2f(cr[tid*4+k]) * wr[tid*4+k];
    LM[tid] = a;
    __syncthreads();
    for (int off = 128; off >= 1; off >>= 1){
        if (tid < off) LM[tid] += LM[tid+off];
        __syncthreads();
    }
    if (tid == 0){
        float tl = LM[0] + fcb[y];
        float nll = lse - tl;
        int valid = (y != 0);
        ws[OFF_NLL + m] = valid ? nll : 0.f;
        ws[OFF_CNT + m] = valid ? 1.f : 0.f;
    }
}

// ------------------------------------------------------------------ finalize
__global__ void k_fin(const float* __restrict__ ws, float* __restrict__ out){
    __shared__ float red[256];
    int tid = threadIdx.x;
    float lt = 0.f;
    if (tid < TM1){
        float s = 0.f, c = 0.f;
        for (int b=0;b<NB;b++){
            s += ws[OFF_NLL + tid*NB + b];
            c += ws[OFF_CNT + tid*NB + b];
        }
        lt = s / fmaxf(c, 1.f);
    }
    red[tid] = lt;
    __syncthreads();
    for (int off=128; off>=1; off>>=1){
        if (tid < off) red[tid] += red[tid+off];
        __syncthreads();
    }
    if (tid == 0) out[0] = red[0] / (float)TM1;
}

// -------------------------------------------------------------------- launch
extern "C" void kernel_launch(void* const* d_in, const int* in_sizes, int n_in,
                              void* d_out, int out_size, void* d_ws, size_t ws_size,
                              hipStream_t stream) {
    const int*   X     = (const int*)  d_in[0];
    const float* enc   = (const float*)d_in[1];
    const float* hid   = (const float*)d_in[2];
    const float* cel   = (const float*)d_in[3];
    const float* emb   = (const float*)d_in[4];
    const float* Wih0  = (const float*)d_in[5];
    const float* Whh0  = (const float*)d_in[6];
    const float* bih0  = (const float*)d_in[7];
    const float* bhh0  = (const float*)d_in[8];
    const float* Wih1  = (const float*)d_in[9];
    const float* Whh1  = (const float*)d_in[10];
    const float* bih1  = (const float*)d_in[11];
    const float* bhh1  = (const float*)d_in[12];
    const float* attnW = (const float*)d_in[13];
    const float* attnb = (const float*)d_in[14];
    const float* v     = (const float*)d_in[15];
    const float* fcW   = (const float*)d_in[16];
    const float* fcb   = (const float*)d_in[17];
    float* ws  = (float*)d_ws;
    float* out = (float*)d_out;

    static int smem_set = 0;
    if (!smem_set){
        (void)hipFuncSetAttribute((const void*)k_scan,
                            hipFuncAttributeMaxDynamicSharedMemorySize, SMEM_BYTES);
        smem_set = 1;
    }

    k_init<<<277, 256, 0, stream>>>(hid, cel, ws);
    k_prep<<<1024, 256, 0, stream>>>(attnW, ws);
    k_encw<<<dim3(8,64), 256, 0, stream>>>(enc, attnW, attnb, ws);
    k_g0x<<<dim3(32,64), 256, 0, stream>>>(X, emb, Wih0, bih0, bhh0, ws);

    void* args[] = {(void*)&enc, (void*)&Whh0, (void*)&Wih1, (void*)&Whh1,
                    (void*)&bih1, (void*)&bhh1, (void*)&v, (void*)&ws};
    (void)hipLaunchCooperativeKernel((const void*)k_scan, dim3(NLSTM + NATTN), dim3(512),
                               args, SMEM_BYTES, stream);

    k_fc<<<dim3(32, NT128), 256, 0, stream>>>(fcW, fcb, ws);
    k_row<<<NROWS, 256, 0, stream>>>(X, fcW, fcb, ws);
    k_fin<<<1, 256, 0, stream>>>(ws, out);
}